// Round 1
// baseline (3796.672 us; speedup 1.0000x reference)
//
#include <hip/hip_runtime.h>

// Problem constants (fixed by setup_inputs): im0 [B,C,H,W] fp32,
// flow [B,H,W,2] fp32, out [B,C,H,W] fp32.
constexpr int B_ = 4;
constexpr int C_ = 3;
constexpr int H_ = 1024;   // power of two -> cheap index math
constexpr int W_ = 1920;
constexpr int HW_ = H_ * W_;

__device__ __forceinline__ void splat3(float* __restrict__ out, int base_b,
                                       int xi, int yi, float w,
                                       float s0, float s1, float s2) {
    if (xi >= 0 && xi < W_ && yi >= 0 && yi < H_) {
        const int o = base_b + yi * W_ + xi;
        // native global_atomic_add_f32 (no CAS loop)
        unsafeAtomicAdd(out + o,            s0 * w);
        unsafeAtomicAdd(out + o + HW_,      s1 * w);
        unsafeAtomicAdd(out + o + 2 * HW_,  s2 * w);
    }
}

__global__ __launch_bounds__(256) void forward_warp_kernel(
    const float* __restrict__ im0,
    const float2* __restrict__ flow,   // [B,H,W,2] viewed as float2
    const int* __restrict__ mode_p,
    float* __restrict__ out) {
    const int x = blockIdx.x * 256 + threadIdx.x;
    if (x >= W_) return;
    const int by = blockIdx.y;          // = b*H + y
    const int y  = by & (H_ - 1);
    const int b  = by >> 10;            // H_ == 1024

    const int pix = by * W_ + x;        // (b*H + y)*W + x
    const float2 f = flow[pix];
    const float tx = (float)x + f.x;
    const float ty = (float)y + f.y;

    // Source channels (coalesced; stride HW_ between channels)
    const int sidx = b * C_ * HW_ + y * W_ + x;
    const float s0 = im0[sidx];
    const float s1 = im0[sidx + HW_];
    const float s2 = im0[sidx + 2 * HW_];

    const int base_b = b * C_ * HW_;
    const int mode = *mode_p;           // wave-uniform

    if (mode == 1) {
        // Nearest: jnp.round = round-half-to-even = rintf (default rounding)
        const int xi = (int)rintf(tx);
        const int yi = (int)rintf(ty);
        splat3(out, base_b, xi, yi, 1.0f, s0, s1, s2);
    } else {
        const float xf = floorf(tx);
        const float yf = floorf(ty);
        const int x0 = (int)xf;
        const int y0 = (int)yf;
        const float wx1 = tx - xf, wy1 = ty - yf;
        const float wx0 = 1.0f - wx1, wy0 = 1.0f - wy1;
        splat3(out, base_b, x0,     y0,     wx0 * wy0, s0, s1, s2);
        splat3(out, base_b, x0 + 1, y0,     wx1 * wy0, s0, s1, s2);
        splat3(out, base_b, x0,     y0 + 1, wx0 * wy1, s0, s1, s2);
        splat3(out, base_b, x0 + 1, y0 + 1, wx1 * wy1, s0, s1, s2);
    }
}

extern "C" void kernel_launch(void* const* d_in, const int* in_sizes, int n_in,
                              void* d_out, int out_size, void* d_ws, size_t ws_size,
                              hipStream_t stream) {
    const float*  im0  = (const float*)d_in[0];
    const float2* flow = (const float2*)d_in[1];
    // d_in[2] = flowback (unused by the forward splat)
    const int*    mode = (const int*)d_in[3];
    float* out = (float*)d_out;

    // Output is accumulated via atomics -> must start from zero every call
    // (harness re-poisons d_out with 0xAA before each timed launch).
    (void)hipMemsetAsync(d_out, 0, (size_t)out_size * sizeof(float), stream);

    dim3 grid((W_ + 255) / 256, B_ * H_);
    forward_warp_kernel<<<grid, dim3(256), 0, stream>>>(im0, flow, mode, out);
}

// Round 2
// 731.633 us; speedup vs baseline: 5.1893x; 5.1893x over previous
//
#include <hip/hip_runtime.h>

// Problem constants (fixed by setup_inputs): im0 [B,C,H,W] fp32,
// flow [B,H,W,2] fp32, out [B,C,H,W] fp32.
constexpr int B_ = 4;
constexpr int C_ = 3;
constexpr int H_ = 1024;
constexpr int W_ = 1920;
constexpr int HW_ = H_ * W_;

// Tile geometry: block of 256 threads owns TW x TH pixels; splats are
// accumulated in an LDS tile extended by halo R on each side, one channel
// at a time. R=16 covers |flow| up to 16 px (flow ~ N(0,5); beyond-halo
// splats take the rare global-atomic fallback path).
constexpr int TW = 128;
constexpr int TH = 64;
constexpr int R  = 16;
constexpr int EW = TW + 2 * R;      // 160
constexpr int EH = TH + 2 * R;      // 96
constexpr int ECELLS = EW * EH;     // 15360 cells -> 61440 B LDS (2 blocks/CU)

static_assert(W_ % TW == 0 && H_ % TH == 0, "exact tiling assumed");

__global__ __launch_bounds__(256) void forward_warp_tiled(
    const float* __restrict__ im0,
    const float2* __restrict__ flow,
    const int* __restrict__ mode_p,
    float* __restrict__ out) {
    __shared__ float tile[ECELLS];

    const int tx0 = blockIdx.x * TW;
    const int ty0 = blockIdx.y * TH;
    const int b   = blockIdx.z;
    const int mode = *mode_p;               // wave-uniform
    const int ex0 = tx0 - R;                // global coord of ext-tile origin
    const int ey0 = ty0 - R;

    for (int c = 0; c < C_; ++c) {
        // --- zero the LDS tile ---
        for (int i = threadIdx.x; i < ECELLS; i += 256) tile[i] = 0.0f;
        __syncthreads();

        const float* im0c = im0 + ((size_t)(b * C_ + c)) * HW_;
        float* outc = out + ((size_t)(b * C_ + c)) * HW_;

        // --- splat this block's pixels (one channel) ---
        for (int p = threadIdx.x; p < TW * TH; p += 256) {
            const int lx = p & (TW - 1);
            const int ly = p >> 7;          // TW == 128
            const int x = tx0 + lx;
            const int y = ty0 + ly;
            const float2 f = flow[(size_t)(b * H_ + y) * W_ + x];
            const float s = im0c[y * W_ + x];
            const float px = (float)x + f.x;
            const float py = (float)y + f.y;

            int   cx[4], cy[4];
            float cw[4];
            int ncorn;
            if (mode == 1) {
                cx[0] = (int)rintf(px);
                cy[0] = (int)rintf(py);
                cw[0] = 1.0f;
                ncorn = 1;
            } else {
                const float xf = floorf(px), yf = floorf(py);
                const int x0 = (int)xf, y0i = (int)yf;
                const float wx1 = px - xf, wy1 = py - yf;
                const float wx0 = 1.0f - wx1, wy0 = 1.0f - wy1;
                cx[0] = x0;     cy[0] = y0i;     cw[0] = wx0 * wy0;
                cx[1] = x0 + 1; cy[1] = y0i;     cw[1] = wx1 * wy0;
                cx[2] = x0;     cy[2] = y0i + 1; cw[2] = wx0 * wy1;
                cx[3] = x0 + 1; cy[3] = y0i + 1; cw[3] = wx1 * wy1;
                ncorn = 4;
            }
            for (int k = 0; k < ncorn; ++k) {
                const int exi = cx[k] - ex0;
                const int eyi = cy[k] - ey0;
                const float v = s * cw[k];
                if ((unsigned)exi < (unsigned)EW && (unsigned)eyi < (unsigned)EH) {
                    atomicAdd(&tile[eyi * EW + exi], v);   // ds_add_f32
                } else if ((unsigned)cx[k] < (unsigned)W_ &&
                           (unsigned)cy[k] < (unsigned)H_) {
                    unsafeAtomicAdd(outc + cy[k] * W_ + cx[k], v); // rare
                }
            }
        }
        __syncthreads();

        // --- flush ext tile to global (dense, coalesced atomics) ---
        for (int i = threadIdx.x; i < ECELLS; i += 256) {
            const float v = tile[i];
            if (v != 0.0f) {
                const int exi = i % EW;
                const int eyi = i / EW;
                const int gx = ex0 + exi;
                const int gy = ey0 + eyi;
                if ((unsigned)gx < (unsigned)W_ && (unsigned)gy < (unsigned)H_)
                    unsafeAtomicAdd(outc + gy * W_ + gx, v);
            }
        }
        __syncthreads();   // before re-zeroing for next channel
    }
}

extern "C" void kernel_launch(void* const* d_in, const int* in_sizes, int n_in,
                              void* d_out, int out_size, void* d_ws, size_t ws_size,
                              hipStream_t stream) {
    const float*  im0  = (const float*)d_in[0];
    const float2* flow = (const float2*)d_in[1];
    // d_in[2] = flowback (unused by the forward splat)
    const int*    mode = (const int*)d_in[3];
    float* out = (float*)d_out;

    // Output accumulates via atomics -> zero it every call (harness poisons
    // d_out with 0xAA before each timed launch).
    (void)hipMemsetAsync(d_out, 0, (size_t)out_size * sizeof(float), stream);

    dim3 grid(W_ / TW, H_ / TH, B_);
    forward_warp_tiled<<<grid, dim3(256), 0, stream>>>(im0, flow, mode, out);
}